// Round 9
// baseline (470.891 us; speedup 1.0000x reference)
//
#include <hip/hip_runtime.h>
#include <hip/hip_bf16.h>

// RPN head: conv3x3(512->512)+ReLU, then 1x1 cls(18)+2-way softmax and 1x1 bbox(36).
// conv = bf16 MFMA implicit GEMM, 256x256 tile, 8 waves (2Mx4N), BK=64, dbuf 128KB.
// R9: ONE-PHASE-AHEAD ds_read pipeline. Each phase issues the NEXT quadrant's
// ds_reads, then MFMAs the current quadrant (operands loaded last phase). No
// lgkmcnt(0) asm: the compiler's auto-waits become counted lgkmcnt(4/8), so
// phase-k reads drain UNDER phase-k MFMA instead of serializing before it.

typedef __bf16 bf16_t;
typedef __attribute__((ext_vector_type(8))) __bf16 bf16x8;
typedef __attribute__((ext_vector_type(4))) __bf16 bf16x4;
typedef __attribute__((ext_vector_type(4))) float f32x4;

#define HW 3800
#define NPOS (8 * HW)
#define XP_IMG (52 * 78 * 512)

__device__ __forceinline__ void gload_lds16(const bf16_t* g, char* l) {
  __builtin_amdgcn_global_load_lds(
      (const __attribute__((address_space(1))) unsigned int*)g,
      (__attribute__((address_space(3))) unsigned int*)l, 16, 0, 0);
}

// base_feat [8][512][50][76] f32 -> Xp [8][52][78][512] bf16.
__global__ __launch_bounds__(256) void pad_nhwc(const float* __restrict__ x,
                                                bf16_t* __restrict__ Xp) {
  const int t = threadIdx.x;
  const int blk = blockIdx.x;
  if (blk < 1600) {
    __shared__ __align__(16) bf16_t tile[76][136];  // [w][c], 272B rows
    const int cb = blk & 3;
    int r = blk >> 2;
    const int h = r % 50, b = r / 50;
#pragma unroll
    for (int it = 0; it < 10; ++it) {
      int idx = it * 256 + t;
      if (idx < 2432) {
        int c = idx / 19, w4 = idx - c * 19;
        const float4 v = *(const float4*)(x +
            (((size_t)(b * 512 + cb * 128 + c)) * 50 + h) * 76 + w4 * 4);
        tile[w4 * 4 + 0][c] = (bf16_t)v.x;
        tile[w4 * 4 + 1][c] = (bf16_t)v.y;
        tile[w4 * 4 + 2][c] = (bf16_t)v.z;
        tile[w4 * 4 + 3][c] = (bf16_t)v.w;
      }
    }
    __syncthreads();
#pragma unroll
    for (int it = 0; it < 5; ++it) {
      int idx = it * 256 + t;
      if (idx < 1216) {
        int w = idx >> 4, c8 = idx & 15;
        bf16x8 v = *(const bf16x8*)&tile[w][c8 * 8];
        *(bf16x8*)(Xp + ((size_t)(b * 52 + h + 1) * 78 + (w + 1)) * 512 +
                   cb * 128 + c8 * 8) = v;
      }
    }
  } else {
    const int blk2 = blk - 1600;            // 16 halo blocks
    const int b = blk2 >> 1, half = blk2 & 1;
    bf16x8 z;
#pragma unroll
    for (int j = 0; j < 8; ++j) z[j] = (bf16_t)0.f;
#pragma unroll
    for (int it = 0; it < 32; ++it) {
      int idx = it * 256 + t;
      int q = half * 128 + (idx >> 6);
      int c8 = idx & 63;
      int h, w;
      if (q < 78)       { h = 0;           w = q; }
      else if (q < 156) { h = 51;          w = q - 78; }
      else if (q < 206) { h = q - 156 + 1; w = 0; }
      else              { h = q - 206 + 1; w = 77; }
      *(bf16x8*)(Xp + ((size_t)(b * 52 + h) * 78 + w) * 512 + c8 * 8) = z;
    }
  }
}

// conv_w [512][512][3][3] f32 -> Wt [9][co][ci] bf16.
__global__ __launch_bounds__(256) void wtrans(const float* __restrict__ cw,
                                              bf16_t* __restrict__ Wt) {
  __shared__ bf16_t lw[4608];
  const int t = threadIdx.x;
  const int co = blockIdx.x;
  const float* src = cw + (size_t)co * 4608;
#pragma unroll
  for (int it = 0; it < 18; ++it) {
    int idx = it * 256 + t;
    lw[idx] = (bf16_t)src[idx];
  }
  __syncthreads();
#pragma unroll
  for (int s = 0; s < 9; ++s) {
    int ci = t * 2;
    bf16_t v0 = lw[ci * 9 + s], v1 = lw[(ci + 1) * 9 + s];
    bf16_t* dst = Wt + ((size_t)s * 512 + co) * 512 + ci;
    dst[0] = v0; dst[1] = v1;
  }
}

// cls_w [18][512], bbox_w [36][512] f32 -> Whb [64][512] bf16, rows permuted.
__global__ __launch_bounds__(256) void whb_build(const float* __restrict__ clsw,
                                                 const float* __restrict__ boxw,
                                                 bf16_t* __restrict__ Whb) {
  int t = blockIdx.x * 256 + threadIdx.x;   // 64*512 = 32768
  int ci = t & 511; int row = t >> 9;
  float v = 0.f;
  if (row < 18) {
    int a = row >> 1, logit = row & 1;
    v = clsw[(logit * 9 + a) * 512 + ci];
  } else if (row < 54) {
    v = boxw[(row - 18) * 512 + ci];
  }
  Whb[(size_t)row * 512 + ci] = (bf16_t)v;
}

// implicit-GEMM conv3x3: 256co x 256pos, BK=64, 8 waves (2Mx4N), dbuf 128KB,
// one-phase-ahead pipelined quadrant loop over 72 K-tiles.
__global__ __launch_bounds__(512, 2) void conv3x3(const bf16_t* __restrict__ Xp,
                                                  const bf16_t* __restrict__ Wt,
                                                  const float* __restrict__ convb,
                                                  bf16_t* __restrict__ rc2) {
  // buffer q at q*65536: A rows 0..255 at [row*128], B at [32768 + row*128]
  __shared__ __align__(16) char smem[131072];
  const int tid = threadIdx.x;
  const int lane = tid & 63;
  const int wv = tid >> 6;          // 0..7
  const int wm = wv >> 2;           // 0..1  (co half)
  const int wn = wv & 3;            // 0..3  (pos quarter)
  const int lm = lane & 15, lg = lane >> 4;

  // XCD swizzle: 240 blocks, 240%8==0 -> one image per XCD
  const int raw = blockIdx.x;
  const int wg = (raw & 7) * 30 + (raw >> 3);
  const int b = wg / 30;
  const int rem = wg - b * 30;
  const int co_base = (rem & 1) * 256;
  const int pos_base = (rem >> 1) * 256;
  const bf16_t* XpB = Xp + (size_t)b * XP_IMG;

  // ---- staging descriptors (same as R8) ----
  // A half mh: striped rows {0..63,128..191} (mh=0 == frag rows a0-3) /
  //            {64..127,192..255} (mh=1 == a4-7).
  int aSrc[2][2], aDst[2][2];
#pragma unroll
  for (int mh = 0; mh < 2; ++mh)
#pragma unroll
    for (int i = 0; i < 2; ++i) {
      int d = i * 512 + tid;
      int rl = d >> 3, p = d & 7;
      int rp = ((rl >> 6) << 7) + mh * 64 + (rl & 63);
      int c = p ^ (rp & 7);                       // pre-swizzled SOURCE chunk
      aSrc[mh][i] = (co_base + rp) * 512 + c * 8;
      aDst[mh][i] = rp * 128 + p * 16;            // linear LDS dest
    }
  // B half f: striped rows {q*64 + f*32 + 0..31} (f=0 == b0-1 rows, f=1 == b2-3).
  int bSpa[2][2], bCc[2][2], bDst[2][2];
#pragma unroll
  for (int f = 0; f < 2; ++f)
#pragma unroll
    for (int i = 0; i < 2; ++i) {
      int d = i * 512 + tid;
      int rl = d >> 3, p = d & 7;
      int rp = ((rl >> 5) << 6) + f * 32 + (rl & 31);
      int c = p ^ (rp & 7);
      int m = pos_base + rp; if (m > HW - 1) m = HW - 1;   // tail clamp
      bSpa[f][i] = (m / 76) * 78 + (m - (m / 76) * 76);
      bCc[f][i] = c * 8;
      bDst[f][i] = 32768 + rp * 128 + p * 16;
    }

  // fragment read offsets (XOR chunk swizzle)
  const int koff0 = (lg ^ (lm & 7)) << 4;
  const int koff1 = ((4 + lg) ^ (lm & 7)) << 4;
  int aOff[8], bOff[4];
#pragma unroll
  for (int m = 0; m < 8; ++m) aOff[m] = (wm * 128 + m * 16 + lm) * 128;
#pragma unroll
  for (int n = 0; n < 4; ++n) bOff[n] = 32768 + (wn * 64 + n * 16 + lm) * 128;

  f32x4 acc[8][4];
#pragma unroll
  for (int i = 0; i < 8; ++i)
#pragma unroll
    for (int j = 0; j < 4; ++j) acc[i][j] = (f32x4){0.f, 0.f, 0.f, 0.f};

  // operand register sets (one-phase-ahead lifetimes, all disjoint per tile)
  bf16x8 ar_lo[4][2], ar_hi[4][2], br01[2][2], br23[2][2];

#define STAGE_A(KT, BUF, MH) {                                                  \
    const int s_ = (KT) >> 3, cb_ = (KT) & 7;                                   \
    const bf16_t* p_ = Wt + (size_t)s_ * 262144 + cb_ * 64;                     \
    _Pragma("unroll")                                                           \
    for (int i_ = 0; i_ < 2; ++i_)                                              \
      gload_lds16(p_ + aSrc[MH][i_], (BUF) + aDst[MH][i_]);                     \
  }
#define STAGE_B(KT, BUF, F) {                                                   \
    const int s_ = (KT) >> 3, cb_ = (KT) & 7;                                   \
    const int sp_ = (s_ / 3) * 78 + (s_ - (s_ / 3) * 3);                        \
    _Pragma("unroll")                                                           \
    for (int i_ = 0; i_ < 2; ++i_)                                              \
      gload_lds16(XpB + (size_t)(bSpa[F][i_] + sp_) * 512 + bCc[F][i_] +        \
                      cb_ * 64,                                                 \
                  (BUF) + bDst[F][i_]);                                         \
  }
#define RD_ALO(BASE)                                                            \
    _Pragma("unroll")                                                           \
    for (int m_ = 0; m_ < 4; ++m_) {                                            \
      ar_lo[m_][0] = *(const bf16x8*)((BASE) + aOff[m_] + koff0);               \
      ar_lo[m_][1] = *(const bf16x8*)((BASE) + aOff[m_] + koff1);               \
    }
#define RD_AHI(BASE)                                                            \
    _Pragma("unroll")                                                           \
    for (int m_ = 0; m_ < 4; ++m_) {                                            \
      ar_hi[m_][0] = *(const bf16x8*)((BASE) + aOff[4 + m_] + koff0);           \
      ar_hi[m_][1] = *(const bf16x8*)((BASE) + aOff[4 + m_] + koff1);           \
    }
#define RD_B01(BASE)                                                            \
    _Pragma("unroll")                                                           \
    for (int n_ = 0; n_ < 2; ++n_) {                                            \
      br01[n_][0] = *(const bf16x8*)((BASE) + bOff[n_] + koff0);                \
      br01[n_][1] = *(const bf16x8*)((BASE) + bOff[n_] + koff1);                \
    }
#define RD_B23(BASE)                                                            \
    _Pragma("unroll")                                                           \
    for (int n_ = 0; n_ < 2; ++n_) {                                            \
      br23[n_][0] = *(const bf16x8*)((BASE) + bOff[2 + n_] + koff0);            \
      br23[n_][1] = *(const bf16x8*)((BASE) + bOff[2 + n_] + koff1);            \
    }
#define MQ(AARR, AOFS, BARR, NOFS)                                              \
    _Pragma("unroll")                                                           \
    for (int m_ = 0; m_ < 4; ++m_)                                              \
      _Pragma("unroll")                                                         \
      for (int n_ = 0; n_ < 2; ++n_)                                            \
        _Pragma("unroll")                                                       \
        for (int k_ = 0; k_ < 2; ++k_)                                          \
          acc[(AOFS) + m_][(NOFS) + n_] =                                       \
              __builtin_amdgcn_mfma_f32_16x16x32_bf16(                          \
                  AARR[m_][k_], BARR[n_][k_], acc[(AOFS) + m_][(NOFS) + n_],    \
                  0, 0, 0);
#define SCB __builtin_amdgcn_sched_barrier(0);
#define BAR __builtin_amdgcn_s_barrier();
#define PRIO1 __builtin_amdgcn_s_setprio(1);
#define PRIO0 __builtin_amdgcn_s_setprio(0);
#define VM8 asm volatile("s_waitcnt vmcnt(8)" ::: "memory");
#define VM0 asm volatile("s_waitcnt vmcnt(0)" ::: "memory");
#define VMNONE

// One tile TT computed from BUF; D-phase prefetches next tile's ar_lo from NBUF.
// Region-free map: b01,b23 read @A -> staged @B; a_lo read @prev-D -> staged @B;
// a_hi read @B -> staged @C. vmcnt(8) @C drains tile TT+1's 8 stage-loads
// (TT+2's 8 remain in flight), making NBUF safe for the D-phase read.
#define DO_TILE(TT, BUF, NBUF, STG, WC, LDN) {                                  \
    /* A: reads for Q2/Q3 era; MFMA Q1 on prev-phase operands */                \
    RD_B01(BUF) RD_B23(BUF)                                                     \
    SCB PRIO1 MQ(ar_lo, 0, br01, 0) PRIO0 BAR                                   \
    /* B: read a_hi; 6 stage-gloads; MFMA Q2 */                                 \
    RD_AHI(BUF)                                                                 \
    if (STG) { STAGE_A((TT) + 2, BUF, 0) STAGE_B((TT) + 2, BUF, 0)              \
               STAGE_B((TT) + 2, BUF, 1) }                                      \
    SCB PRIO1 MQ(ar_lo, 0, br23, 2) PRIO0 BAR                                   \
    /* C: 2 stage-gloads; MFMA Q3; counted vmcnt boundary */                    \
    if (STG) STAGE_A((TT) + 2, BUF, 1)                                          \
    SCB PRIO1 MQ(ar_hi, 4, br23, 2) PRIO0 WC BAR                                \
    /* D: prefetch next tile's ar_lo; MFMA Q4 (all operands held) */            \
    if (LDN) RD_ALO(NBUF)                                                       \
    SCB PRIO1 MQ(ar_hi, 4, br01, 0) PRIO0 BAR                                   \
  }

  // prologue: full stages for tiles 0,1; drain tile0 (counted); preload ar_lo(0)
  STAGE_A(0, smem, 0) STAGE_A(0, smem, 1) STAGE_B(0, smem, 0) STAGE_B(0, smem, 1)
  STAGE_A(1, smem + 65536, 0) STAGE_A(1, smem + 65536, 1)
  STAGE_B(1, smem + 65536, 0) STAGE_B(1, smem + 65536, 1)
  VM8
  BAR
  RD_ALO(smem)

  for (int it = 0; it < 35; ++it) {     // tiles 0..69; stages up to tile 71
    const int E = 2 * it;
    DO_TILE(E,     smem,         smem + 65536, true, VM8, true)
    DO_TILE(E + 1, smem + 65536, smem,         true, VM8, true)
  }
  DO_TILE(70, smem,         smem + 65536, false, VM0, true)   // drain stage(71)
  DO_TILE(71, smem + 65536, smem,         false, VMNONE, false)

#undef DO_TILE
#undef STAGE_A
#undef STAGE_B
#undef RD_ALO
#undef RD_AHI
#undef RD_B01
#undef RD_B23
#undef MQ
#undef SCB
#undef BAR
#undef PRIO1
#undef PRIO0
#undef VM8
#undef VM0
#undef VMNONE

  // epilogue: bias + ReLU, store NHWC rc2[(b*HW+pos)][co], 8B per fragment
  const size_t outRow = (size_t)b * HW;
#pragma unroll
  for (int m = 0; m < 8; ++m) {
    const int co = co_base + wm * 128 + m * 16 + lg * 4;
    const float4 bias = *(const float4*)(convb + co);
#pragma unroll
    for (int n = 0; n < 4; ++n) {
      const int pos = pos_base + wn * 64 + n * 16 + lm;
      if (pos < HW) {
        bf16x4 v;
        float z0 = acc[m][n][0] + bias.x; v[0] = (bf16_t)(z0 > 0.f ? z0 : 0.f);
        float z1 = acc[m][n][1] + bias.y; v[1] = (bf16_t)(z1 > 0.f ? z1 : 0.f);
        float z2 = acc[m][n][2] + bias.z; v[2] = (bf16_t)(z2 > 0.f ? z2 : 0.f);
        float z3 = acc[m][n][3] + bias.w; v[3] = (bf16_t)(z3 > 0.f ? z3 : 0.f);
        *(bf16x4*)(rc2 + (outRow + pos) * 512 + co) = v;
      }
    }
  }
}

// heads: C[64co][128pos] = Whb[64][512] x rc2[pos][512], fused bias/softmax/store.
__global__ __launch_bounds__(256) void heads_mfma(const bf16_t* __restrict__ rc2,
                                                  const bf16_t* __restrict__ Whb,
                                                  const float* __restrict__ clsb,
                                                  const float* __restrict__ boxb,
                                                  float* __restrict__ out) {
  __shared__ __align__(16) char smem[24576];  // A:[0,8K) B:[8K,24K)
  const int t = threadIdx.x, lane = t & 63, wv = t >> 6;
  const int lm = lane & 15, lg = lane >> 4, lx = lane & 7;
  const int pos_base = blockIdx.x * 128;

  int aSrc[2], bSrc[4];
#pragma unroll
  for (int i = 0; i < 2; ++i) {
    int d = i * 256 + t;
    int r = d >> 3, p = d & 7, c = p ^ (r & 7);
    aSrc[i] = r * 512 + c * 8;
  }
#pragma unroll
  for (int i = 0; i < 4; ++i) {
    int d = i * 256 + t;
    int r = d >> 3, p = d & 7, c = p ^ (r & 7);
    int pg = pos_base + r; if (pg > NPOS - 1) pg = NPOS - 1;
    bSrc[i] = pg * 512 + c * 8;
  }

  f32x4 acc[4][2];
#pragma unroll
  for (int i = 0; i < 4; ++i)
#pragma unroll
    for (int j = 0; j < 2; ++j) acc[i][j] = (f32x4){0.f, 0.f, 0.f, 0.f};

  for (int cb = 0; cb < 8; ++cb) {
    __syncthreads();
#pragma unroll
    for (int i = 0; i < 2; ++i) {
      int d = i * 256 + t;
      gload_lds16(Whb + aSrc[i] + cb * 64, &smem[d * 16]);
    }
#pragma unroll
    for (int i = 0; i < 4; ++i) {
      int d = i * 256 + t;
      gload_lds16(rc2 + (size_t)bSrc[i] + cb * 64, &smem[8192 + d * 16]);
    }
    __syncthreads();
#pragma unroll
    for (int ks = 0; ks < 2; ++ks) {
      const int koff = ((ks * 4 + lg) ^ lx) << 4;
      bf16x8 af[4], bfr[2];
#pragma unroll
      for (int f = 0; f < 4; ++f)
        af[f] = *(const bf16x8*)&smem[(f * 16 + lm) * 128 + koff];
#pragma unroll
      for (int f = 0; f < 2; ++f)
        bfr[f] = *(const bf16x8*)&smem[8192 + (wv * 32 + f * 16 + lm) * 128 + koff];
#pragma unroll
      for (int fa = 0; fa < 4; ++fa)
#pragma unroll
        for (int fb = 0; fb < 2; ++fb)
          acc[fa][fb] = __builtin_amdgcn_mfma_f32_16x16x32_bf16(
              af[fa], bfr[fb], acc[fa][fb], 0, 0, 0);
    }
  }

  float* boxOut = out + (size_t)8 * 18 * HW;
#pragma unroll
  for (int fb = 0; fb < 2; ++fb) {
    const int pg = pos_base + wv * 32 + fb * 16 + lm;
    if (pg < NPOS) {
      const int b = pg / HW;
      const int m = pg - b * HW;
#pragma unroll
      for (int fa = 0; fa < 4; ++fa) {
        const int base = fa * 16 + lg * 4;
#pragma unroll
        for (int pr = 0; pr < 2; ++pr) {
          const int row0 = base + pr * 2;
          const float v0 = acc[fa][fb][pr * 2];
          const float v1 = acc[fa][fb][pr * 2 + 1];
          if (row0 < 18) {
            const int a = row0 >> 1;
            const float s0 = v0 + clsb[a];
            const float s1 = v1 + clsb[9 + a];
            const float mx = fmaxf(s0, s1);
            const float e0 = expf(s0 - mx), e1 = expf(s1 - mx);
            const float inv = 1.0f / (e0 + e1);
            out[((size_t)(b * 18 + a)) * HW + m] = e0 * inv;
            out[((size_t)(b * 18 + 9 + a)) * HW + m] = e1 * inv;
          } else if (row0 < 54) {
            const int c0 = row0 - 18;
            boxOut[((size_t)(b * 36 + c0)) * HW + m] = v0 + boxb[c0];
            boxOut[((size_t)(b * 36 + c0 + 1)) * HW + m] = v1 + boxb[c0 + 1];
          }
        }
      }
    }
  }
}

extern "C" void kernel_launch(void* const* d_in, const int* in_sizes, int n_in,
                              void* d_out, int out_size, void* d_ws, size_t ws_size,
                              hipStream_t stream) {
  (void)in_sizes; (void)n_in; (void)out_size; (void)ws_size;
  const float* base_feat = (const float*)d_in[0];
  const float* conv_w = (const float*)d_in[4];
  const float* conv_b = (const float*)d_in[5];
  const float* cls_w  = (const float*)d_in[6];
  const float* cls_b  = (const float*)d_in[7];
  const float* bbox_w = (const float*)d_in[8];
  const float* bbox_b = (const float*)d_in[9];

  char* ws = (char*)d_ws;
  bf16_t* Xp  = (bf16_t*)(ws);                 // 8*52*78*512*2   = 33,226,752 B
  bf16_t* Wt  = (bf16_t*)(ws + 33226752);      // 9*512*512*2     =  4,718,592 B
  bf16_t* rc2 = (bf16_t*)(ws + 37945344);      // 30400*512*2     = 31,129,600 B (NHWC)
  bf16_t* Whb = (bf16_t*)(ws + 69074944);      // 64*512*2        =     65,536 B

  hipLaunchKernelGGL(pad_nhwc,   dim3(1616), dim3(256), 0, stream, base_feat, Xp);
  hipLaunchKernelGGL(wtrans,     dim3(512),  dim3(256), 0, stream, conv_w, Wt);
  hipLaunchKernelGGL(whb_build,  dim3(128),  dim3(256), 0, stream, cls_w, bbox_w, Whb);
  hipLaunchKernelGGL(conv3x3,    dim3(240),  dim3(512), 0, stream, Xp, Wt, conv_b, rc2);
  hipLaunchKernelGGL(heads_mfma, dim3(238),  dim3(256), 0, stream, rc2, Whb, cls_b, bbox_b,
                     (float*)d_out);
}

// Round 10
// 158.275 us; speedup vs baseline: 2.9751x; 2.9751x over previous
//
#include <hip/hip_runtime.h>
#include <hip/hip_bf16.h>

// RPN head: conv3x3(512->512)+ReLU, then 1x1 cls(18)+2-way softmax and 1x1 bbox(36).
// conv = bf16 MFMA implicit GEMM, 256x256 tile, 8 waves, double-buffered LDS,
// 4-phase pipeline (R4 structure -- best measured: 141.8us, MfmaUtil 42.7%).
// Preps merged into one kernel to cut launch overhead.

typedef __bf16 bf16_t;
typedef __attribute__((ext_vector_type(8))) __bf16 bf16x8;
typedef __attribute__((ext_vector_type(4))) __bf16 bf16x4;
typedef __attribute__((ext_vector_type(4))) float f32x4;

#define HW 3800
#define NPOS (8 * HW)
#define XP_IMG (52 * 78 * 512)

__device__ __forceinline__ void gload_lds16(const bf16_t* g, char* l) {
  __builtin_amdgcn_global_load_lds(
      (const __attribute__((address_space(1))) unsigned int*)g,
      (__attribute__((address_space(3))) unsigned int*)l, 16, 0, 0);
}

// Merged prep: blocks 0..1599 pad-transpose, 1600..1615 halo-zero,
// 1616..2127 wtrans (co = blk-1616), 2128..2255 whb_build.
__global__ __launch_bounds__(256) void prep_all(const float* __restrict__ x,
                                                const float* __restrict__ cw,
                                                const float* __restrict__ clsw,
                                                const float* __restrict__ boxw,
                                                bf16_t* __restrict__ Xp,
                                                bf16_t* __restrict__ Wt,
                                                bf16_t* __restrict__ Whb) {
  __shared__ __align__(16) bf16_t tile[76][136];  // pad path
  __shared__ bf16_t lw[4608];                     // wtrans path
  const int t = threadIdx.x;
  const int blk = blockIdx.x;
  if (blk < 1600) {
    const int cb = blk & 3;
    int r = blk >> 2;
    const int h = r % 50, b = r / 50;
#pragma unroll
    for (int it = 0; it < 10; ++it) {
      int idx = it * 256 + t;
      if (idx < 2432) {
        int c = idx / 19, w4 = idx - c * 19;
        const float4 v = *(const float4*)(x +
            (((size_t)(b * 512 + cb * 128 + c)) * 50 + h) * 76 + w4 * 4);
        tile[w4 * 4 + 0][c] = (bf16_t)v.x;
        tile[w4 * 4 + 1][c] = (bf16_t)v.y;
        tile[w4 * 4 + 2][c] = (bf16_t)v.z;
        tile[w4 * 4 + 3][c] = (bf16_t)v.w;
      }
    }
    __syncthreads();
#pragma unroll
    for (int it = 0; it < 5; ++it) {
      int idx = it * 256 + t;
      if (idx < 1216) {
        int w = idx >> 4, c8 = idx & 15;
        bf16x8 v = *(const bf16x8*)&tile[w][c8 * 8];
        *(bf16x8*)(Xp + ((size_t)(b * 52 + h + 1) * 78 + (w + 1)) * 512 +
                   cb * 128 + c8 * 8) = v;
      }
    }
  } else if (blk < 1616) {
    const int blk2 = blk - 1600;            // 16 halo blocks
    const int b = blk2 >> 1, half = blk2 & 1;
    bf16x8 z;
#pragma unroll
    for (int j = 0; j < 8; ++j) z[j] = (bf16_t)0.f;
#pragma unroll
    for (int it = 0; it < 32; ++it) {
      int idx = it * 256 + t;
      int q = half * 128 + (idx >> 6);
      int c8 = idx & 63;
      int h, w;
      if (q < 78)       { h = 0;           w = q; }
      else if (q < 156) { h = 51;          w = q - 78; }
      else if (q < 206) { h = q - 156 + 1; w = 0; }
      else              { h = q - 206 + 1; w = 77; }
      *(bf16x8*)(Xp + ((size_t)(b * 52 + h) * 78 + w) * 512 + c8 * 8) = z;
    }
  } else if (blk < 2128) {
    const int co = blk - 1616;              // wtrans: one block per co
    const float* src = cw + (size_t)co * 4608;
#pragma unroll
    for (int it = 0; it < 18; ++it) {
      int idx = it * 256 + t;
      lw[idx] = (bf16_t)src[idx];
    }
    __syncthreads();
#pragma unroll
    for (int s = 0; s < 9; ++s) {
      int ci = t * 2;
      bf16_t v0 = lw[ci * 9 + s], v1 = lw[(ci + 1) * 9 + s];
      bf16_t* dst = Wt + ((size_t)s * 512 + co) * 512 + ci;
      dst[0] = v0; dst[1] = v1;
    }
  } else {
    int g = (blk - 2128) * 256 + t;         // whb_build: 64*512 = 32768
    int ci = g & 511; int row = g >> 9;
    float v = 0.f;
    if (row < 18) {
      int a = row >> 1, logit = row & 1;
      v = clsw[(logit * 9 + a) * 512 + ci];
    } else if (row < 54) {
      v = boxw[(row - 18) * 512 + ci];
    }
    Whb[(size_t)row * 512 + ci] = (bf16_t)v;
  }
}

// implicit-GEMM conv3x3: 256co x 256pos tile, BK=64, 8 waves (2Mx4N),
// double-buffered 128KiB LDS, 4-phase pipelined K-loop (72 K-tiles). [R4]
__global__ __launch_bounds__(512) void conv3x3(const bf16_t* __restrict__ Xp,
                                               const bf16_t* __restrict__ Wt,
                                               const float* __restrict__ convb,
                                               bf16_t* __restrict__ rc2) {
  __shared__ __align__(16) char smem[131072];  // buf0: A[0,32K) B[32K,64K); buf1 at 64K
  const int tid = threadIdx.x;
  const int lane = tid & 63;
  const int wv = tid >> 6;          // 0..7
  const int wm = wv >> 2;           // 0..1  (co half)
  const int wn = wv & 3;            // 0..3  (pos quarter)
  const int lm = lane & 15, lg = lane >> 4;

  // XCD swizzle: 240 blocks, 240%8==0 -> one image per XCD
  const int raw = blockIdx.x;
  const int wg = (raw & 7) * 30 + (raw >> 3);
  const int b = wg / 30;
  const int rem = wg - b * 30;
  const int co_base = (rem & 1) * 256;
  const int pos_base = (rem >> 1) * 256;

  // staging descriptors: chunk d = i*512+tid; row r=d>>3, phys p=d&7, logical c=p^(r&7)
  int aSrc[4], hB[4], wB[4], cB[4];
#pragma unroll
  for (int i = 0; i < 4; ++i) {
    int d = i * 512 + tid;
    int r = d >> 3, p = d & 7, c = p ^ (r & 7);
    aSrc[i] = (co_base + r) * 512 + c * 8;
    int m = pos_base + r; if (m > HW - 1) m = HW - 1;   // tail clamp (masked at store)
    hB[i] = m / 76; wB[i] = m - (m / 76) * 76; cB[i] = c * 8;
  }
  const bf16_t* XpB = Xp + (size_t)b * XP_IMG;

  // fragment read offsets (XOR-swizzled, conflict-free)
  int aOff[8], bOff[4], koffs[2];
#pragma unroll
  for (int m = 0; m < 8; ++m) aOff[m] = (wm * 128 + m * 16 + lm) * 128;
#pragma unroll
  for (int n = 0; n < 4; ++n) bOff[n] = 32768 + (wn * 64 + n * 16 + lm) * 128;
#pragma unroll
  for (int ks = 0; ks < 2; ++ks) koffs[ks] = ((ks * 4 + lg) ^ (lm & 7)) << 4;

  f32x4 acc[8][4];
#pragma unroll
  for (int i = 0; i < 8; ++i)
#pragma unroll
    for (int j = 0; j < 4; ++j) acc[i][j] = (f32x4){0.f, 0.f, 0.f, 0.f};

  // prologue: stage K-tile 0 (s=0, cb=0) into buf0
#pragma unroll
  for (int i = 0; i < 4; ++i)
    gload_lds16(Wt + aSrc[i], smem + (i * 512 + tid) * 16);
#pragma unroll
  for (int i = 0; i < 4; ++i)
    gload_lds16(XpB + (hB[i] * 78 + wB[i]) * 512 + cB[i],
                smem + 32768 + (i * 512 + tid) * 16);
  asm volatile("s_waitcnt vmcnt(0)" ::: "memory");
  __builtin_amdgcn_s_barrier();
  __builtin_amdgcn_sched_barrier(0);

  for (int kt = 0; kt < 72; ++kt) {            // K-tile = (s = kt>>3, cb = kt&7)
    const int cur = kt & 1;
    const char* Ab = smem + cur * 65536;       // bOff[] includes the +32768 B offset
    char* Anxt = smem + (cur ^ 1) * 65536;
    const int tn = kt + 1;
    const int sn = tn >> 3, cbn = tn & 7;

    bf16x8 pa[4], pb[4];

    // ---- phase 0: issue A-stage(t+1); read B(ks0)+A(mh0,ks0); MFMA acc[0..3]
    if (tn < 72) {
      const bf16_t* As = Wt + (size_t)sn * 262144 + cbn * 64;
#pragma unroll
      for (int i = 0; i < 4; ++i)
        gload_lds16(As + aSrc[i], Anxt + (i * 512 + tid) * 16);
    }
#pragma unroll
    for (int n = 0; n < 4; ++n) pb[n] = *(const bf16x8*)(Ab + bOff[n] + koffs[0]);
#pragma unroll
    for (int f = 0; f < 4; ++f) pa[f] = *(const bf16x8*)(Ab + aOff[f] + koffs[0]);
    __builtin_amdgcn_s_setprio(1);
#pragma unroll
    for (int f = 0; f < 4; ++f)
#pragma unroll
      for (int n = 0; n < 4; ++n)
        acc[f][n] = __builtin_amdgcn_mfma_f32_16x16x32_bf16(pa[f], pb[n], acc[f][n], 0, 0, 0);
    __builtin_amdgcn_s_setprio(0);
    __builtin_amdgcn_s_barrier();

    // ---- phase 1: issue B-stage(t+1); read A(mh1,ks0); MFMA acc[4..7] (pb held)
    if (tn < 72) {
      const int kh = sn / 3, kw = sn - kh * 3;
#pragma unroll
      for (int i = 0; i < 4; ++i) {
        int off = ((hB[i] + kh) * 78 + (wB[i] + kw)) * 512 + cB[i] + cbn * 64;
        gload_lds16(XpB + off, Anxt + 32768 + (i * 512 + tid) * 16);
      }
    }
#pragma unroll
    for (int f = 0; f < 4; ++f) pa[f] = *(const bf16x8*)(Ab + aOff[4 + f] + koffs[0]);
    __builtin_amdgcn_s_setprio(1);
#pragma unroll
    for (int f = 0; f < 4; ++f)
#pragma unroll
      for (int n = 0; n < 4; ++n)
        acc[4 + f][n] = __builtin_amdgcn_mfma_f32_16x16x32_bf16(pa[f], pb[n], acc[4 + f][n], 0, 0, 0);
    __builtin_amdgcn_s_setprio(0);
    __builtin_amdgcn_s_barrier();

    // ---- phase 2: read B(ks1)+A(mh0,ks1); MFMA acc[0..3]
#pragma unroll
    for (int n = 0; n < 4; ++n) pb[n] = *(const bf16x8*)(Ab + bOff[n] + koffs[1]);
#pragma unroll
    for (int f = 0; f < 4; ++f) pa[f] = *(const bf16x8*)(Ab + aOff[f] + koffs[1]);
    __builtin_amdgcn_s_setprio(1);
#pragma unroll
    for (int f = 0; f < 4; ++f)
#pragma unroll
      for (int n = 0; n < 4; ++n)
        acc[f][n] = __builtin_amdgcn_mfma_f32_16x16x32_bf16(pa[f], pb[n], acc[f][n], 0, 0, 0);
    __builtin_amdgcn_s_setprio(0);
    __builtin_amdgcn_s_barrier();

    // ---- phase 3: read A(mh1,ks1); MFMA acc[4..7]
#pragma unroll
    for (int f = 0; f < 4; ++f) pa[f] = *(const bf16x8*)(Ab + aOff[4 + f] + koffs[1]);
    __builtin_amdgcn_s_setprio(1);
#pragma unroll
    for (int f = 0; f < 4; ++f)
#pragma unroll
      for (int n = 0; n < 4; ++n)
        acc[4 + f][n] = __builtin_amdgcn_mfma_f32_16x16x32_bf16(pa[f], pb[n], acc[4 + f][n], 0, 0, 0);
    __builtin_amdgcn_s_setprio(0);

    // ---- boundary: drain of t+1's stage loads, then all-wave visibility
    asm volatile("s_waitcnt vmcnt(0)" ::: "memory");
    __builtin_amdgcn_s_barrier();
    __builtin_amdgcn_sched_barrier(0);
  }

  // epilogue: bias + ReLU, store NHWC rc2[(b*HW+pos)][co], 8B per fragment
  const size_t outRow = (size_t)b * HW;
#pragma unroll
  for (int m = 0; m < 8; ++m) {
    const int co = co_base + wm * 128 + m * 16 + lg * 4;
    const float4 bias = *(const float4*)(convb + co);
#pragma unroll
    for (int n = 0; n < 4; ++n) {
      const int pos = pos_base + wn * 64 + n * 16 + lm;
      if (pos < HW) {
        bf16x4 v;
        float z0 = acc[m][n][0] + bias.x; v[0] = (bf16_t)(z0 > 0.f ? z0 : 0.f);
        float z1 = acc[m][n][1] + bias.y; v[1] = (bf16_t)(z1 > 0.f ? z1 : 0.f);
        float z2 = acc[m][n][2] + bias.z; v[2] = (bf16_t)(z2 > 0.f ? z2 : 0.f);
        float z3 = acc[m][n][3] + bias.w; v[3] = (bf16_t)(z3 > 0.f ? z3 : 0.f);
        *(bf16x4*)(rc2 + (outRow + pos) * 512 + co) = v;
      }
    }
  }
}

// heads: C[64co][128pos] = Whb[64][512] x rc2[pos][512], fused bias/softmax/store.
__global__ __launch_bounds__(256) void heads_mfma(const bf16_t* __restrict__ rc2,
                                                  const bf16_t* __restrict__ Whb,
                                                  const float* __restrict__ clsb,
                                                  const float* __restrict__ boxb,
                                                  float* __restrict__ out) {
  __shared__ __align__(16) char smem[24576];  // A:[0,8K) B:[8K,24K)
  const int t = threadIdx.x, lane = t & 63, wv = t >> 6;
  const int lm = lane & 15, lg = lane >> 4, lx = lane & 7;
  const int pos_base = blockIdx.x * 128;

  int aSrc[2], bSrc[4];
#pragma unroll
  for (int i = 0; i < 2; ++i) {
    int d = i * 256 + t;
    int r = d >> 3, p = d & 7, c = p ^ (r & 7);
    aSrc[i] = r * 512 + c * 8;
  }
#pragma unroll
  for (int i = 0; i < 4; ++i) {
    int d = i * 256 + t;
    int r = d >> 3, p = d & 7, c = p ^ (r & 7);
    int pg = pos_base + r; if (pg > NPOS - 1) pg = NPOS - 1;
    bSrc[i] = pg * 512 + c * 8;
  }

  f32x4 acc[4][2];
#pragma unroll
  for (int i = 0; i < 4; ++i)
#pragma unroll
    for (int j = 0; j < 2; ++j) acc[i][j] = (f32x4){0.f, 0.f, 0.f, 0.f};

  for (int cb = 0; cb < 8; ++cb) {
    __syncthreads();
#pragma unroll
    for (int i = 0; i < 2; ++i) {
      int d = i * 256 + t;
      gload_lds16(Whb + aSrc[i] + cb * 64, &smem[d * 16]);
    }
#pragma unroll
    for (int i = 0; i < 4; ++i) {
      int d = i * 256 + t;
      gload_lds16(rc2 + (size_t)bSrc[i] + cb * 64, &smem[8192 + d * 16]);
    }
    __syncthreads();
#pragma unroll
    for (int ks = 0; ks < 2; ++ks) {
      const int koff = ((ks * 4 + lg) ^ lx) << 4;
      bf16x8 af[4], bfr[2];
#pragma unroll
      for (int f = 0; f < 4; ++f)
        af[f] = *(const bf16x8*)&smem[(f * 16 + lm) * 128 + koff];
#pragma unroll
      for (int f = 0; f < 2; ++f)
        bfr[f] = *(const bf16x8*)&smem[8192 + (wv * 32 + f * 16 + lm) * 128 + koff];
#pragma unroll
      for (int fa = 0; fa < 4; ++fa)
#pragma unroll
        for (int fb = 0; fb < 2; ++fb)
          acc[fa][fb] = __builtin_amdgcn_mfma_f32_16x16x32_bf16(
              af[fa], bfr[fb], acc[fa][fb], 0, 0, 0);
    }
  }

  float* boxOut = out + (size_t)8 * 18 * HW;
#pragma unroll
  for (int fb = 0; fb < 2; ++fb) {
    const int pg = pos_base + wv * 32 + fb * 16 + lm;
    if (pg < NPOS) {
      const int b = pg / HW;
      const int m = pg - b * HW;
#pragma unroll
      for (int fa = 0; fa < 4; ++fa) {
        const int base = fa * 16 + lg * 4;
#pragma unroll
        for (int pr = 0; pr < 2; ++pr) {
          const int row0 = base + pr * 2;
          const float v0 = acc[fa][fb][pr * 2];
          const float v1 = acc[fa][fb][pr * 2 + 1];
          if (row0 < 18) {
            const int a = row0 >> 1;
            const float s0 = v0 + clsb[a];
            const float s1 = v1 + clsb[9 + a];
            const float mx = fmaxf(s0, s1);
            const float e0 = expf(s0 - mx), e1 = expf(s1 - mx);
            const float inv = 1.0f / (e0 + e1);
            out[((size_t)(b * 18 + a)) * HW + m] = e0 * inv;
            out[((size_t)(b * 18 + 9 + a)) * HW + m] = e1 * inv;
          } else if (row0 < 54) {
            const int c0 = row0 - 18;
            boxOut[((size_t)(b * 36 + c0)) * HW + m] = v0 + boxb[c0];
            boxOut[((size_t)(b * 36 + c0 + 1)) * HW + m] = v1 + boxb[c0 + 1];
          }
        }
      }
    }
  }
}

extern "C" void kernel_launch(void* const* d_in, const int* in_sizes, int n_in,
                              void* d_out, int out_size, void* d_ws, size_t ws_size,
                              hipStream_t stream) {
  (void)in_sizes; (void)n_in; (void)out_size; (void)ws_size;
  const float* base_feat = (const float*)d_in[0];
  const float* conv_w = (const float*)d_in[4];
  const float* conv_b = (const float*)d_in[5];
  const float* cls_w  = (const float*)d_in[6];
  const float* cls_b  = (const float*)d_in[7];
  const float* bbox_w = (const float*)d_in[8];
  const float* bbox_b = (const float*)d_in[9];

  char* ws = (char*)d_ws;
  bf16_t* Xp  = (bf16_t*)(ws);                 // 8*52*78*512*2   = 33,226,752 B
  bf16_t* Wt  = (bf16_t*)(ws + 33226752);      // 9*512*512*2     =  4,718,592 B
  bf16_t* rc2 = (bf16_t*)(ws + 37945344);      // 30400*512*2     = 31,129,600 B (NHWC)
  bf16_t* Whb = (bf16_t*)(ws + 69074944);      // 64*512*2        =     65,536 B

  hipLaunchKernelGGL(prep_all,   dim3(2256), dim3(256), 0, stream,
                     base_feat, conv_w, cls_w, bbox_w, Xp, Wt, Whb);
  hipLaunchKernelGGL(conv3x3,    dim3(240),  dim3(512), 0, stream, Xp, Wt, conv_b, rc2);
  hipLaunchKernelGGL(heads_mfma, dim3(238),  dim3(256), 0, stream, rc2, Whb, cls_b, bbox_b,
                     (float*)d_out);
}